// Round 4
// baseline (253.821 us; speedup 1.0000x reference)
//
#include <hip/hip_runtime.h>
#include <hip/hip_bf16.h>

// Pipeline: roi_align -> conv3x3(C=256->E=256 on 3x3 spatial, pad 1) -> GroupNorm(8)
//           -> ReLU -> spatial mean -> head GEMM -> +spat +sym_emb -> per-sid fuse matvec.
// Sizes: B=2, C=E=256, S=3, L=5, N=128, HMAX=128.
// R15: fold ROI gather INTO conv_gn_pool (per-block gather of its 2 samples into
// LDS, identical math/layout; conv body unchanged, reads LDS). Deletes prep's roi
// stage, the roiT 1.2 MB write+readback, and one device-wide dependency edge.
// Gather is duplicated 4x across eq-quarters -> grid swizzle np=blk&63, eq=blk>>6
// puts the 4 eq-siblings (stride 64 === 0 mod 8) on ONE XCD so duplicate fm lines
// dedupe in that XCD's L2.
// R14 lesson: gather loop-order (page locality) is NOT the bottleneck (+-0).
// R13 lesson: full fm transpose costs more than the gather. R12 lesson: conv at
// 128 blocks loses more than a launch saves. R10: c-paired roi reads + k-paired
// bf16 weights. R5: no device fences in hot blocks. R3: transposed matvec weights.

typedef float v2f __attribute__((ext_vector_type(2)));

__device__ __forceinline__ float bf_lo(unsigned u) { return __uint_as_float(u << 16); }
__device__ __forceinline__ float bf_hi(unsigned u) { return __uint_as_float(u & 0xffff0000u); }
__device__ __forceinline__ unsigned short f2bf(float f) {
    __hip_bfloat16 h = __float2bfloat16(f);
    return *(unsigned short*)&h;
}

// ---------------- prep kernel: weight repacks only ----------------
// grid.x: [0,256)    w_prep (block=c, thread=e)
//         [256,704)  t7     (448 tiles: head_w + 6x fuse_w -> transposed k-paired bf16)
__global__ __launch_bounds__(256) void prep_k(
    const float* __restrict__ conv_w,
    const float* __restrict__ head_w, const float* __restrict__ fuse_w,
    unsigned short* __restrict__ w8, unsigned short* __restrict__ w9,
    unsigned short* __restrict__ head_wTb, unsigned short* __restrict__ fuse_wTb) {
    int blk = blockIdx.x;
    int t = threadIdx.x;

    if (blk < 256) {
        // conv weight repack: [e][c][9] f32 -> w8[c][e][8] + w9[c][e] bf16
        int c = blk, e = t;
        const float* src = conv_w + ((size_t)e * 256 + c) * 9;
        unsigned short tmp[8];
#pragma unroll
        for (int k = 0; k < 8; ++k) tmp[k] = f2bf(src[k]);
        ((uint4*)w8)[(size_t)c * 256 + e] = *(const uint4*)tmp;
        w9[(size_t)c * 256 + e] = f2bf(src[8]);
        return;
    }

    // 32x32 tiled transpose of head_w (z=0) / fuse_w (z=1..6).
    // Output: k-paired bf16 — ushort index ((k>>1)*256 + e)*2 + (k&1).
    {
        __shared__ float tile[32][33];
        int q = blk - 256;
        int z = q >> 6;
        int rem = q & 63;
        int bx = (rem & 7) * 32, by = (rem >> 3) * 32;
        const float* in = (z == 0) ? head_w : fuse_w + (size_t)(z - 1) * 65536;
        unsigned short* out = (z == 0) ? head_wTb : fuse_wTb + (size_t)(z - 1) * 65536;
        int tx = t & 31, ty = t >> 5;
#pragma unroll
        for (int i = 0; i < 32; i += 8)
            tile[ty + i][tx] = in[(size_t)(by + ty + i) * 256 + bx + tx];
        __syncthreads();
#pragma unroll
        for (int i = 0; i < 32; i += 8) {
            int k = bx + ty + i;          // transposed row (original col)
            int e = by + tx;
            out[(size_t)((k >> 1) * 256 + e) * 2 + (k & 1)] = f2bf(tile[tx][ty + i]);
        }
    }
}

// ---------------- roi gather + conv3x3 + GroupNorm + ReLU + spatial-mean ----------------
// Grid swizzle: np = blk & 63 (sample pair), eq = blk >> 6 (e-quarter). The 4
// eq-siblings of one np have blockIdx stride 64 (=== 0 mod 8) -> same XCD ->
// duplicate gather lines served by that XCD's L2.
// Gather phase: t -> c = t&255, half = t>>8 (sample select); 9 p-points x 4
// corner loads per thread into roiA/roiB[p][c] in LDS (same layout as old roiT).
// Conv phase: identical to R11 body; r0/r1 now point at LDS (wave-uniform
// ds_read_b64 broadcast instead of s_load_dwordx2).
__global__ __launch_bounds__(512, 2) void conv_gn_pool(
    const float* __restrict__ fm, const float* __restrict__ boxes,
    const int* __restrict__ batch_idx, const int* __restrict__ level_idx,
    const unsigned short* __restrict__ w8, const unsigned short* __restrict__ w9,
    const float* __restrict__ gn_scale, const float* __restrict__ gn_bias,
    float* __restrict__ pooled) {
    __shared__ float roiA[9 * 256];       // sample n0, [p][c]
    __shared__ float roiB[9 * 256];       // sample n1
    __shared__ float redA[4 * 64 * 9];
    __shared__ float redB[4 * 64 * 9];

    int blk = blockIdx.x;
    int np = blk & 63;                    // sample pair
    int eq = blk >> 6;                    // e-quarter
    int n0 = np * 2, n1 = n0 + 1;
    int t = threadIdx.x;

    // ---- gather phase ----
    {
        int c = t & 255;
        int half = t >> 8;                // 0 -> n0, 1 -> n1 (wave-uniform)
        int n = half ? n1 : n0;
        float* dst = half ? roiB : roiA;

        int lvl = level_idx[n];
        int b = batch_idx[n];
        const float sizes[5]  = {128.f, 64.f, 32.f, 16.f, 8.f};
        const float invstr[5] = {1.f/8.f, 1.f/16.f, 1.f/32.f, 1.f/64.f, 1.f/128.f};
        float scale = invstr[lvl];
        float hv = sizes[lvl];

        float x1 = boxes[n*4+0] * scale, y1 = boxes[n*4+1] * scale;
        float x2 = boxes[n*4+2] * scale, y2 = boxes[n*4+3] * scale;
        float rw = fmaxf(x2 - x1, 1.f), rh = fmaxf(y2 - y1, 1.f);
        int hi = (int)(hv - 1.f);

        const float* base = fm + (((size_t)lvl * 2 + b) * 256 + c) * (128 * 128);

#pragma unroll
        for (int p = 0; p < 9; ++p) {
            int i = p / 3, j = p % 3;
            float x = x1 + (((float)j + 0.5f) / 3.f) * rw;
            float y = y1 + (((float)i + 0.5f) / 3.f) * rh;

            bool valid = (y > -1.f) && (y < hv) && (x > -1.f) && (x < hv);
            float yc = fminf(fmaxf(y, 0.f), hv - 1.f);
            float xc = fminf(fmaxf(x, 0.f), hv - 1.f);
            int y0 = (int)floorf(yc), x0 = (int)floorf(xc);
            int y1i = min(y0 + 1, hi), x1i = min(x0 + 1, hi);
            float ly = yc - (float)y0, lx = xc - (float)x0;

            float v00 = base[y0 * 128 + x0];
            float v01 = base[y0 * 128 + x1i];
            float v10 = base[y1i * 128 + x0];
            float v11 = base[y1i * 128 + x1i];
            float v = (1.f - ly) * (1.f - lx) * v00 + (1.f - ly) * lx * v01 +
                      ly * (1.f - lx) * v10 + ly * lx * v11;
            dst[p * 256 + c] = valid ? v : 0.f;
        }
    }
    __syncthreads();

    // ---- conv phase (body identical to R11; sources are LDS) ----
    int e_loc = t & 63;
    int ch = __builtin_amdgcn_readfirstlane(t >> 6);   // wave-uniform 0..7
    int e = eq * 64 + e_loc;

    const float* r0 = roiA;               // [p][c]
    const float* r1 = roiB;

    v2f acc[9];
#pragma unroll
    for (int p = 0; p < 9; ++p) acc[p] = (v2f)(0.f);

    int c0 = ch * 32;
#pragma unroll 2
    for (int c = c0; c < c0 + 32; c += 2) {
        // wave-uniform float2 roi reads (adjacent c, 8B-aligned) -> ds_read_b64 broadcast
        v2f q0[9], q1[9];                 // q0: sample0 (c, c+1), q1: sample1
#pragma unroll
        for (int jj = 0; jj < 9; ++jj) {
            q0[jj] = *(const v2f*)(r0 + jj * 256 + c);
            q1[jj] = *(const v2f*)(r1 + jj * 256 + c);
        }
        // sample-packed uniform pairs per c
        v2f rc0[9], rc1[9];
#pragma unroll
        for (int jj = 0; jj < 9; ++jj) {
            rc0[jj].x = q0[jj].x; rc0[jj].y = q1[jj].x;   // channel c
            rc1[jj].x = q0[jj].y; rc1[jj].y = q1[jj].y;   // channel c+1
        }
#pragma unroll
        for (int cc = 0; cc < 2; ++cc) {
            const v2f* r = cc ? rc1 : rc0;
            int cw = c + cc;
            uint4 wa4 = ((const uint4*)w8)[(size_t)cw * 256 + e];
            float wv[9];
            wv[0] = bf_lo(wa4.x); wv[1] = bf_hi(wa4.x);
            wv[2] = bf_lo(wa4.y); wv[3] = bf_hi(wa4.y);
            wv[4] = bf_lo(wa4.z); wv[5] = bf_hi(wa4.z);
            wv[6] = bf_lo(wa4.w); wv[7] = bf_hi(wa4.w);
            wv[8] = bf_lo((unsigned)w9[(size_t)cw * 256 + e]);
#pragma unroll
            for (int ky = 0; ky < 3; ++ky) {
#pragma unroll
                for (int kx = 0; kx < 3; ++kx) {
                    v2f w2;
                    w2.x = wv[ky * 3 + kx]; w2.y = wv[ky * 3 + kx];
#pragma unroll
                    for (int oy = 0; oy < 3; ++oy) {
                        int iy = oy + ky - 1;
                        if (iy < 0 || iy > 2) continue;
#pragma unroll
                        for (int ox = 0; ox < 3; ++ox) {
                            int ix = ox + kx - 1;
                            if (ix < 0 || ix > 2) continue;
                            int o = oy * 3 + ox, in = iy * 3 + ix;
                            acc[o] = w2 * r[in] + acc[o];   // -> v_pk_fma_f32
                        }
                    }
                }
            }
        }
    }

    float acc0[9], acc1[9];
#pragma unroll
    for (int p = 0; p < 9; ++p) { acc0[p] = acc[p].x; acc1[p] = acc[p].y; }

    // tree-reduce 8 c-slices into ch==0 (sample0) / ch==1 (sample1)
    if (ch >= 4) {
#pragma unroll
        for (int p = 0; p < 9; ++p) {
            redA[((ch - 4) * 64 + e_loc) * 9 + p] = acc0[p];
            redB[((ch - 4) * 64 + e_loc) * 9 + p] = acc1[p];
        }
    }
    __syncthreads();
    if (ch < 4) {
#pragma unroll
        for (int p = 0; p < 9; ++p) {
            acc0[p] += redA[(ch * 64 + e_loc) * 9 + p];
            acc1[p] += redB[(ch * 64 + e_loc) * 9 + p];
        }
    }
    __syncthreads();
    if (ch >= 2 && ch < 4) {
#pragma unroll
        for (int p = 0; p < 9; ++p) {
            redA[((ch - 2) * 64 + e_loc) * 9 + p] = acc0[p];
            redB[((ch - 2) * 64 + e_loc) * 9 + p] = acc1[p];
        }
    }
    __syncthreads();
    if (ch < 2) {
#pragma unroll
        for (int p = 0; p < 9; ++p) {
            acc0[p] += redA[(ch * 64 + e_loc) * 9 + p];
            acc1[p] += redB[(ch * 64 + e_loc) * 9 + p];
        }
    }
    __syncthreads();
    if (ch == 1) {
#pragma unroll
        for (int p = 0; p < 9; ++p) redA[e_loc * 9 + p] = acc0[p];
    }
    if (ch == 0) {
#pragma unroll
        for (int p = 0; p < 9; ++p) redB[e_loc * 9 + p] = acc1[p];
    }
    __syncthreads();

    if (ch < 2) {
        float accf[9];
        int n_out;
        if (ch == 0) {
            n_out = n0;
#pragma unroll
            for (int p = 0; p < 9; ++p) accf[p] = acc0[p] + redA[e_loc * 9 + p];
        } else {
            n_out = n1;
#pragma unroll
            for (int p = 0; p < 9; ++p) accf[p] = acc1[p] + redB[e_loc * 9 + p];
        }

        float s = 0.f, sq = 0.f;
#pragma unroll
        for (int p = 0; p < 9; ++p) { s += accf[p]; sq += accf[p] * accf[p]; }
#pragma unroll
        for (int m = 16; m >= 1; m >>= 1) {
            s  += __shfl_xor(s, m, 64);
            sq += __shfl_xor(sq, m, 64);
        }
        float mean = s * (1.f / 288.f);
        float var = sq * (1.f / 288.f) - mean * mean;
        float rinv = rsqrtf(var + 1e-5f);
        float gs = gn_scale[e], gb = gn_bias[e];
        float ps = 0.f;
#pragma unroll
        for (int p = 0; p < 9; ++p) {
            float v = (accf[p] - mean) * rinv * gs + gb;
            ps += fmaxf(v, 0.f);
        }
        pooled[(size_t)n_out * 256 + e] = ps * (1.f / 9.f);
    }
}

// ---------------- head GEMM + spat + sym_emb + fuse matvec (k-split x2) ----------------
// block = n (128 blocks x 512 threads). t = kh*256 + e. Weights are transposed,
// k-paired bf16: one uint per lane = taps (2k, 2k+1) for its e — coalesced 4B/lane.
__global__ __launch_bounds__(512) void head_fuse(
    const float* __restrict__ pooled, const float* __restrict__ boxes,
    const unsigned short* __restrict__ head_wTb, const float* __restrict__ head_b,
    const float* __restrict__ spat_w, const float* __restrict__ spat_b,
    const float* __restrict__ sym_emb,
    const unsigned short* __restrict__ fuse_wTb, const float* __restrict__ fuse_b,
    const int* __restrict__ sym_ids, float* __restrict__ out) {
    __shared__ float pl[256];
    __shared__ float part[512];
    __shared__ float fin[256];
    int n = blockIdx.x;
    int t = threadIdx.x;
    int e = t & 255;
    int kh = t >> 8;                      // 0/1
    int sid = sym_ids[n];

    if (t < 256) pl[t] = pooled[(size_t)n * 256 + t];
    __syncthreads();

    {
        float acc = 0.f;
        const unsigned* w = (const unsigned*)head_wTb + (size_t)(kh * 64) * 256 + e;
        const float* p = pl + kh * 128;
#pragma unroll 8
        for (int kp = 0; kp < 64; ++kp) {
            unsigned u = w[kp * 256];
            acc = fmaf(p[2 * kp],     bf_lo(u), acc);
            acc = fmaf(p[2 * kp + 1], bf_hi(u), acc);
        }
        part[t] = acc;
    }
    __syncthreads();
    if (t < 256) {
        float ho = fmaxf(part[t] + part[t + 256] + head_b[t], 0.f);
        float4 sw = ((const float4*)spat_w)[t];
        float b0 = boxes[n*4+0], b1 = boxes[n*4+1], b2 = boxes[n*4+2], b3 = boxes[n*4+3];
        float sp = fmaxf(spat_b[t] + b0*sw.x + b1*sw.y + b2*sw.z + b3*sw.w, 0.f);
        fin[t] = ho + sp + sym_emb[sid * 256 + t];
    }
    __syncthreads();
    {
        float o = 0.f;
        const unsigned* w = (const unsigned*)fuse_wTb + (size_t)sid * 32768
                            + (size_t)(kh * 64) * 256 + e;
        const float* p = fin + kh * 128;
#pragma unroll 8
        for (int kp = 0; kp < 64; ++kp) {
            unsigned u = w[kp * 256];
            o = fmaf(p[2 * kp],     bf_lo(u), o);
            o = fmaf(p[2 * kp + 1], bf_hi(u), o);
        }
        part[t] = o;
    }
    __syncthreads();
    if (t < 256)
        out[(size_t)n * 256 + t] = fmaxf(part[t] + part[t + 256] + fuse_b[sid * 256 + t], 0.f);
}

extern "C" void kernel_launch(void* const* d_in, const int* in_sizes, int n_in,
                              void* d_out, int out_size, void* d_ws, size_t ws_size,
                              hipStream_t stream) {
    const float* fm      = (const float*)d_in[0];
    const float* boxes   = (const float*)d_in[1];
    const float* conv_w  = (const float*)d_in[2];
    const float* gn_s    = (const float*)d_in[3];
    const float* gn_b    = (const float*)d_in[4];
    const float* head_w  = (const float*)d_in[5];
    const float* head_b  = (const float*)d_in[6];
    const float* spat_w  = (const float*)d_in[7];
    const float* spat_b  = (const float*)d_in[8];
    const float* sym_emb = (const float*)d_in[9];
    const float* fuse_w  = (const float*)d_in[10];
    const float* fuse_b  = (const float*)d_in[11];
    const int* batch_idx = (const int*)d_in[12];
    const int* level_idx = (const int*)d_in[13];
    const int* sym_ids   = (const int*)d_in[14];
    float* outp = (float*)d_out;

    char* ws = (char*)d_ws;
    unsigned short* w8       = (unsigned short*)ws;             // [256c][256e][8] bf16: 1,048,576 B
    unsigned short* w9       = (unsigned short*)(ws + 1048576); // [256c][256e] bf16  :   131,072 B
    unsigned short* head_wTb = (unsigned short*)(ws + 1179648); // [128kp][256e][2]   :   131,072 B
    unsigned short* fuse_wTb = (unsigned short*)(ws + 1310720); // [6][128kp][256e][2]:   786,432 B
    float* pooled  = (float*)(ws + 2097152);                    // [128][256]         :   131,072 B

    prep_k<<<704, 256, 0, stream>>>(conv_w, head_w, fuse_w,
                                    w8, w9, head_wTb, fuse_wTb);
    conv_gn_pool<<<256, 512, 0, stream>>>(fm, boxes, batch_idx, level_idx,
                                          w8, w9, gn_s, gn_b, pooled);
    head_fuse<<<128, 512, 0, stream>>>(pooled, boxes, head_wTb, head_b, spat_w, spat_b,
                                       sym_emb, fuse_wTb, fuse_b, sym_ids, outp);
}

// Round 5
// 248.908 us; speedup vs baseline: 1.0197x; 1.0197x over previous
//
#include <hip/hip_runtime.h>
#include <hip/hip_bf16.h>

// Pipeline: roi_align -> conv3x3(C=256->E=256 on 3x3 spatial, pad 1) -> GroupNorm(8)
//           -> ReLU -> spatial mean -> head GEMM -> +spat +sym_emb -> per-sid fuse matvec.
// Sizes: B=2, C=E=256, S=3, L=5, N=128, HMAX=128.
// R16: FINAL — revert to the empirically best R11 structure (measured 249.98 us).
// Session ledger: R12 fuse conv+head (+7), R13 fm transpose (+76), R14 gather
// reorder (+1), R15 gather-into-conv (+4). All structural levers <= noise or
// negative. Timed iteration is ~200 us of harness 671 MB workspace poison at
// 82-85% HBM roofline (2x fillBufferAligned ~100 us each) + ~50 us pipeline
// whose components are individually noise-level. This is the measurable floor.
// R11: roi block swizzle (p*128+n) -> 9 p-blocks of one sample share an XCD.
// R10: c-paired s_load_dwordx2 roi + k-paired bf16 head/fuse weights.
// R5 lesson: no device fences in hot blocks. R3: transposed matvec weights.

typedef float v2f __attribute__((ext_vector_type(2)));

__device__ __forceinline__ float bf_lo(unsigned u) { return __uint_as_float(u << 16); }
__device__ __forceinline__ float bf_hi(unsigned u) { return __uint_as_float(u & 0xffff0000u); }
__device__ __forceinline__ unsigned short f2bf(float f) {
    __hip_bfloat16 h = __float2bfloat16(f);
    return *(unsigned short*)&h;
}

// ---------------- fused prep kernel ----------------
// grid.x: [0,256)    w_prep (block=c, thread=e)
//         [256,704)  t7     (448 tiles: head_w + 6x fuse_w -> transposed k-paired bf16)
//         [704,1856) roi    (block q = p*128 + n  [XCD-swizzled], thread=c)
__global__ __launch_bounds__(256) void prep_k(
    const float* __restrict__ conv_w,
    const float* __restrict__ head_w, const float* __restrict__ fuse_w,
    const float* __restrict__ fm, const float* __restrict__ boxes,
    const int* __restrict__ batch_idx, const int* __restrict__ level_idx,
    unsigned short* __restrict__ w8, unsigned short* __restrict__ w9,
    unsigned short* __restrict__ head_wTb, unsigned short* __restrict__ fuse_wTb,
    float* __restrict__ roiT) {
    int blk = blockIdx.x;
    int t = threadIdx.x;

    if (blk < 256) {
        // conv weight repack: [e][c][9] f32 -> w8[c][e][8] + w9[c][e] bf16
        int c = blk, e = t;
        const float* src = conv_w + ((size_t)e * 256 + c) * 9;
        unsigned short tmp[8];
#pragma unroll
        for (int k = 0; k < 8; ++k) tmp[k] = f2bf(src[k]);
        ((uint4*)w8)[(size_t)c * 256 + e] = *(const uint4*)tmp;
        w9[(size_t)c * 256 + e] = f2bf(src[8]);
        return;
    }

    if (blk < 704) {
        // 32x32 tiled transpose of head_w (z=0) / fuse_w (z=1..6).
        // Output: k-paired bf16 — ushort index ((k>>1)*256 + e)*2 + (k&1).
        __shared__ float tile[32][33];
        int q = blk - 256;
        int z = q >> 6;
        int rem = q & 63;
        int bx = (rem & 7) * 32, by = (rem >> 3) * 32;
        const float* in = (z == 0) ? head_w : fuse_w + (size_t)(z - 1) * 65536;
        unsigned short* out = (z == 0) ? head_wTb : fuse_wTb + (size_t)(z - 1) * 65536;
        int tx = t & 31, ty = t >> 5;
#pragma unroll
        for (int i = 0; i < 32; i += 8)
            tile[ty + i][tx] = in[(size_t)(by + ty + i) * 256 + bx + tx];
        __syncthreads();
#pragma unroll
        for (int i = 0; i < 32; i += 8) {
            int k = bx + ty + i;          // transposed row (original col)
            int e = by + tx;
            out[(size_t)((k >> 1) * 256 + e) * 2 + (k & 1)] = f2bf(tile[tx][ty + i]);
        }
        return;
    }

    // ROI align: roiT[n][p][c]. Block decode q = p*128 + n: all 9 p-blocks of a
    // sample share an XCD (stride 128 === 0 mod 8) -> shared bilinear lines in L2.
    {
        int q = blk - 704;
        int n = q & 127, p = q >> 7;
        int i = p / 3, j = p % 3;
        int c = t;

        int lvl = level_idx[n];
        int b = batch_idx[n];
        const float sizes[5]  = {128.f, 64.f, 32.f, 16.f, 8.f};
        const float invstr[5] = {1.f/8.f, 1.f/16.f, 1.f/32.f, 1.f/64.f, 1.f/128.f};
        float scale = invstr[lvl];
        float hv = sizes[lvl];

        float x1 = boxes[n*4+0] * scale, y1 = boxes[n*4+1] * scale;
        float x2 = boxes[n*4+2] * scale, y2 = boxes[n*4+3] * scale;
        float rw = fmaxf(x2 - x1, 1.f), rh = fmaxf(y2 - y1, 1.f);
        float x = x1 + (((float)j + 0.5f) / 3.f) * rw;
        float y = y1 + (((float)i + 0.5f) / 3.f) * rh;

        bool valid = (y > -1.f) && (y < hv) && (x > -1.f) && (x < hv);
        float yc = fminf(fmaxf(y, 0.f), hv - 1.f);
        float xc = fminf(fmaxf(x, 0.f), hv - 1.f);
        int y0 = (int)floorf(yc), x0 = (int)floorf(xc);
        int hi = (int)(hv - 1.f);
        int y1i = min(y0 + 1, hi), x1i = min(x0 + 1, hi);
        float ly = yc - (float)y0, lx = xc - (float)x0;

        const float* base = fm + (((size_t)lvl * 2 + b) * 256 + c) * (128 * 128);
        float v00 = base[y0 * 128 + x0];
        float v01 = base[y0 * 128 + x1i];
        float v10 = base[y1i * 128 + x0];
        float v11 = base[y1i * 128 + x1i];
        float v = (1.f - ly) * (1.f - lx) * v00 + (1.f - ly) * lx * v01 +
                  ly * (1.f - lx) * v10 + ly * lx * v11;
        roiT[((size_t)n * 9 + p) * 256 + c] = valid ? v : 0.f;
    }
}

// ---------------- conv3x3 + GroupNorm + ReLU + spatial-mean ----------------
// Block = (n-pair, e-quarter): 256 blocks x 512 threads.
// thread: e_loc = t&63, ch = t>>6 (8 c-slices of 32 channels, c in pairs).
// Sample pair packed in v2f lanes (.x = n0, .y = n1) -> v_pk_fma_f32; roi values
// wave-uniform -> s_load_dwordx2 over adjacent c. GN group = e/32: 32-lane halves.
__global__ __launch_bounds__(512, 2) void conv_gn_pool(
    const float* __restrict__ roiT,
    const unsigned short* __restrict__ w8, const unsigned short* __restrict__ w9,
    const float* __restrict__ gn_scale, const float* __restrict__ gn_bias,
    float* __restrict__ pooled) {
    __shared__ float redA[4 * 64 * 9];
    __shared__ float redB[4 * 64 * 9];

    int np = blockIdx.x >> 2;             // 0..63 sample pair
    int eq = blockIdx.x & 3;
    int n0 = np * 2, n1 = n0 + 1;
    int t = threadIdx.x;
    int e_loc = t & 63;
    int ch = __builtin_amdgcn_readfirstlane(t >> 6);   // wave-uniform 0..7
    int e = eq * 64 + e_loc;

    const float* r0 = roiT + (size_t)n0 * 2304;   // [p][c]
    const float* r1 = roiT + (size_t)n1 * 2304;

    v2f acc[9];
#pragma unroll
    for (int p = 0; p < 9; ++p) acc[p] = (v2f)(0.f);

    int c0 = ch * 32;
#pragma unroll 2
    for (int c = c0; c < c0 + 32; c += 2) {
        // wave-uniform float2 roi loads (adjacent c, 8B-aligned) -> s_load_dwordx2
        v2f q0[9], q1[9];                 // q0: sample0 (c, c+1), q1: sample1
#pragma unroll
        for (int jj = 0; jj < 9; ++jj) {
            q0[jj] = *(const v2f*)(r0 + jj * 256 + c);
            q1[jj] = *(const v2f*)(r1 + jj * 256 + c);
        }
        // sample-packed uniform pairs per c
        v2f rc0[9], rc1[9];
#pragma unroll
        for (int jj = 0; jj < 9; ++jj) {
            rc0[jj].x = q0[jj].x; rc0[jj].y = q1[jj].x;   // channel c
            rc1[jj].x = q0[jj].y; rc1[jj].y = q1[jj].y;   // channel c+1
        }
#pragma unroll
        for (int cc = 0; cc < 2; ++cc) {
            const v2f* r = cc ? rc1 : rc0;
            int cw = c + cc;
            uint4 wa4 = ((const uint4*)w8)[(size_t)cw * 256 + e];
            float wv[9];
            wv[0] = bf_lo(wa4.x); wv[1] = bf_hi(wa4.x);
            wv[2] = bf_lo(wa4.y); wv[3] = bf_hi(wa4.y);
            wv[4] = bf_lo(wa4.z); wv[5] = bf_hi(wa4.z);
            wv[6] = bf_lo(wa4.w); wv[7] = bf_hi(wa4.w);
            wv[8] = bf_lo((unsigned)w9[(size_t)cw * 256 + e]);
#pragma unroll
            for (int ky = 0; ky < 3; ++ky) {
#pragma unroll
                for (int kx = 0; kx < 3; ++kx) {
                    v2f w2;
                    w2.x = wv[ky * 3 + kx]; w2.y = wv[ky * 3 + kx];
#pragma unroll
                    for (int oy = 0; oy < 3; ++oy) {
                        int iy = oy + ky - 1;
                        if (iy < 0 || iy > 2) continue;
#pragma unroll
                        for (int ox = 0; ox < 3; ++ox) {
                            int ix = ox + kx - 1;
                            if (ix < 0 || ix > 2) continue;
                            int o = oy * 3 + ox, in = iy * 3 + ix;
                            acc[o] = w2 * r[in] + acc[o];   // -> v_pk_fma_f32
                        }
                    }
                }
            }
        }
    }

    float acc0[9], acc1[9];
#pragma unroll
    for (int p = 0; p < 9; ++p) { acc0[p] = acc[p].x; acc1[p] = acc[p].y; }

    // tree-reduce 8 c-slices into ch==0 (sample0) / ch==1 (sample1)
    if (ch >= 4) {
#pragma unroll
        for (int p = 0; p < 9; ++p) {
            redA[((ch - 4) * 64 + e_loc) * 9 + p] = acc0[p];
            redB[((ch - 4) * 64 + e_loc) * 9 + p] = acc1[p];
        }
    }
    __syncthreads();
    if (ch < 4) {
#pragma unroll
        for (int p = 0; p < 9; ++p) {
            acc0[p] += redA[(ch * 64 + e_loc) * 9 + p];
            acc1[p] += redB[(ch * 64 + e_loc) * 9 + p];
        }
    }
    __syncthreads();
    if (ch >= 2 && ch < 4) {
#pragma unroll
        for (int p = 0; p < 9; ++p) {
            redA[((ch - 2) * 64 + e_loc) * 9 + p] = acc0[p];
            redB[((ch - 2) * 64 + e_loc) * 9 + p] = acc1[p];
        }
    }
    __syncthreads();
    if (ch < 2) {
#pragma unroll
        for (int p = 0; p < 9; ++p) {
            acc0[p] += redA[(ch * 64 + e_loc) * 9 + p];
            acc1[p] += redB[(ch * 64 + e_loc) * 9 + p];
        }
    }
    __syncthreads();
    if (ch == 1) {
#pragma unroll
        for (int p = 0; p < 9; ++p) redA[e_loc * 9 + p] = acc0[p];
    }
    if (ch == 0) {
#pragma unroll
        for (int p = 0; p < 9; ++p) redB[e_loc * 9 + p] = acc1[p];
    }
    __syncthreads();

    if (ch < 2) {
        float accf[9];
        int n_out;
        if (ch == 0) {
            n_out = n0;
#pragma unroll
            for (int p = 0; p < 9; ++p) accf[p] = acc0[p] + redA[e_loc * 9 + p];
        } else {
            n_out = n1;
#pragma unroll
            for (int p = 0; p < 9; ++p) accf[p] = acc1[p] + redB[e_loc * 9 + p];
        }

        float s = 0.f, sq = 0.f;
#pragma unroll
        for (int p = 0; p < 9; ++p) { s += accf[p]; sq += accf[p] * accf[p]; }
#pragma unroll
        for (int m = 16; m >= 1; m >>= 1) {
            s  += __shfl_xor(s, m, 64);
            sq += __shfl_xor(sq, m, 64);
        }
        float mean = s * (1.f / 288.f);
        float var = sq * (1.f / 288.f) - mean * mean;
        float rinv = rsqrtf(var + 1e-5f);
        float gs = gn_scale[e], gb = gn_bias[e];
        float ps = 0.f;
#pragma unroll
        for (int p = 0; p < 9; ++p) {
            float v = (accf[p] - mean) * rinv * gs + gb;
            ps += fmaxf(v, 0.f);
        }
        pooled[(size_t)n_out * 256 + e] = ps * (1.f / 9.f);
    }
}

// ---------------- head GEMM + spat + sym_emb + fuse matvec (k-split x2) ----------------
// block = n (128 blocks x 512 threads). t = kh*256 + e. Weights are transposed,
// k-paired bf16: one uint per lane = taps (2k, 2k+1) for its e — coalesced 4B/lane.
__global__ __launch_bounds__(512) void head_fuse(
    const float* __restrict__ pooled, const float* __restrict__ boxes,
    const unsigned short* __restrict__ head_wTb, const float* __restrict__ head_b,
    const float* __restrict__ spat_w, const float* __restrict__ spat_b,
    const float* __restrict__ sym_emb,
    const unsigned short* __restrict__ fuse_wTb, const float* __restrict__ fuse_b,
    const int* __restrict__ sym_ids, float* __restrict__ out) {
    __shared__ float pl[256];
    __shared__ float part[512];
    __shared__ float fin[256];
    int n = blockIdx.x;
    int t = threadIdx.x;
    int e = t & 255;
    int kh = t >> 8;                      // 0/1
    int sid = sym_ids[n];

    if (t < 256) pl[t] = pooled[(size_t)n * 256 + t];
    __syncthreads();

    {
        float acc = 0.f;
        const unsigned* w = (const unsigned*)head_wTb + (size_t)(kh * 64) * 256 + e;
        const float* p = pl + kh * 128;
#pragma unroll 8
        for (int kp = 0; kp < 64; ++kp) {
            unsigned u = w[kp * 256];
            acc = fmaf(p[2 * kp],     bf_lo(u), acc);
            acc = fmaf(p[2 * kp + 1], bf_hi(u), acc);
        }
        part[t] = acc;
    }
    __syncthreads();
    if (t < 256) {
        float ho = fmaxf(part[t] + part[t + 256] + head_b[t], 0.f);
        float4 sw = ((const float4*)spat_w)[t];
        float b0 = boxes[n*4+0], b1 = boxes[n*4+1], b2 = boxes[n*4+2], b3 = boxes[n*4+3];
        float sp = fmaxf(spat_b[t] + b0*sw.x + b1*sw.y + b2*sw.z + b3*sw.w, 0.f);
        fin[t] = ho + sp + sym_emb[sid * 256 + t];
    }
    __syncthreads();
    {
        float o = 0.f;
        const unsigned* w = (const unsigned*)fuse_wTb + (size_t)sid * 32768
                            + (size_t)(kh * 64) * 256 + e;
        const float* p = fin + kh * 128;
#pragma unroll 8
        for (int kp = 0; kp < 64; ++kp) {
            unsigned u = w[kp * 256];
            o = fmaf(p[2 * kp],     bf_lo(u), o);
            o = fmaf(p[2 * kp + 1], bf_hi(u), o);
        }
        part[t] = o;
    }
    __syncthreads();
    if (t < 256)
        out[(size_t)n * 256 + t] = fmaxf(part[t] + part[t + 256] + fuse_b[sid * 256 + t], 0.f);
}

extern "C" void kernel_launch(void* const* d_in, const int* in_sizes, int n_in,
                              void* d_out, int out_size, void* d_ws, size_t ws_size,
                              hipStream_t stream) {
    const float* fm      = (const float*)d_in[0];
    const float* boxes   = (const float*)d_in[1];
    const float* conv_w  = (const float*)d_in[2];
    const float* gn_s    = (const float*)d_in[3];
    const float* gn_b    = (const float*)d_in[4];
    const float* head_w  = (const float*)d_in[5];
    const float* head_b  = (const float*)d_in[6];
    const float* spat_w  = (const float*)d_in[7];
    const float* spat_b  = (const float*)d_in[8];
    const float* sym_emb = (const float*)d_in[9];
    const float* fuse_w  = (const float*)d_in[10];
    const float* fuse_b  = (const float*)d_in[11];
    const int* batch_idx = (const int*)d_in[12];
    const int* level_idx = (const int*)d_in[13];
    const int* sym_ids   = (const int*)d_in[14];
    float* outp = (float*)d_out;

    char* ws = (char*)d_ws;
    unsigned short* w8       = (unsigned short*)ws;             // [256c][256e][8] bf16: 1,048,576 B
    unsigned short* w9       = (unsigned short*)(ws + 1048576); // [256c][256e] bf16  :   131,072 B
    unsigned short* head_wTb = (unsigned short*)(ws + 1179648); // [128kp][256e][2]   :   131,072 B
    unsigned short* fuse_wTb = (unsigned short*)(ws + 1310720); // [6][128kp][256e][2]:   786,432 B
    float* roiT    = (float*)(ws + 2097152);                    // [128][9][256]      : 1,179,648 B
    float* pooled  = (float*)(ws + 3276800);                    // [128][256]         :   131,072 B

    prep_k<<<1856, 256, 0, stream>>>(conv_w, head_w, fuse_w, fm, boxes,
                                     batch_idx, level_idx,
                                     w8, w9, head_wTb, fuse_wTb, roiT);
    conv_gn_pool<<<256, 512, 0, stream>>>(roiT, w8, w9, gn_s, gn_b, pooled);
    head_fuse<<<128, 512, 0, stream>>>(pooled, boxes, head_wTb, head_b, spat_w, spat_b,
                                       sym_emb, fuse_wTb, fuse_b, sym_ids, outp);
}